// Round 16
// baseline (497.724 us; speedup 1.0000x reference)
//
#include <hip/hip_runtime.h>

#define QDIM 4096
#define NDIM 50000
#define KDIM 1024
#define DDIM 256
#define ABLK 391          // ceil(NDIM/128) argmin blocks
#define TAU  0.3f         // refine margin: ~10 sigma of the fp16 screen noise

typedef _Float16 half8 __attribute__((ext_vector_type(8)));
typedef float    f32x4 __attribute__((ext_vector_type(4)));

// async global->LDS DMA, 16B per lane, linear LDS dest (base + lane*16)
#define GLD16(srcp, dstp)                                                              \
    __builtin_amdgcn_global_load_lds((const __attribute__((address_space(1))) void*)(srcp), \
                                     (__attribute__((address_space(3))) void*)(dstp), 16, 0, 0)

// ---- emulate numpy pairwise sum of squares for n=256 (two 128-halves, 8 accumulators)
__device__ float np_pairwise_sq(const float* a) {
#pragma clang fp contract(off)
    float res[2];
    for (int h = 0; h < 2; ++h) {
        const float* p = a + h * 128;
        float r0 = p[0] * p[0], r1 = p[1] * p[1], r2 = p[2] * p[2], r3 = p[3] * p[3];
        float r4 = p[4] * p[4], r5 = p[5] * p[5], r6 = p[6] * p[6], r7 = p[7] * p[7];
        for (int i = 8; i < 128; i += 8) {
            r0 += p[i + 0] * p[i + 0];
            r1 += p[i + 1] * p[i + 1];
            r2 += p[i + 2] * p[i + 2];
            r3 += p[i + 3] * p[i + 3];
            r4 += p[i + 4] * p[i + 4];
            r5 += p[i + 5] * p[i + 5];
            r6 += p[i + 6] * p[i + 6];
            r7 += p[i + 7] * p[i + 7];
        }
        res[h] = ((r0 + r1) + (r2 + r3)) + ((r4 + r5) + (r6 + r7));
    }
    return res[0] + res[1];
}

// ---- np-f32-exact d2 for one (row, code) pair
__device__ float np_exact_d2(const float* __restrict__ xr, const float* __restrict__ cp,
                             float x2, float c2v) {
    float dot = 0.f;                         // BLAS-style sequential FMA in d-order
    for (int d = 0; d < DDIM; ++d) dot = __builtin_fmaf(cp[d], xr[d], dot);
    return (x2 + c2v) - 2.0f * dot;
}

// ---------------------------------------------------------------- prep+cvt fused: c2np (bit-exact np tree) + fp16 codebook
__global__ __launch_bounds__(256) void prepcvt_kernel(const float* __restrict__ cb,
                                                      float* __restrict__ c2np,
                                                      _Float16* __restrict__ cbh,
                                                      int* __restrict__ refCtr) {
#pragma clang fp contract(off)
    int tid = threadIdx.x;
    int code = blockIdx.x * 16 + (tid >> 4);
    int l = tid & 15;
    // --- c2: 16 lanes/row, lane = np accumulator j of half h; shfl tree rebuilds np's exact order
    {
        int h = l >> 3, j = l & 7;
        const float* p = cb + (size_t)code * DDIM + h * 128;
        float v0 = p[j];
        float r = v0 * v0;
        for (int i = 8; i < 128; i += 8) { float v = p[i + j]; r = r + v * v; }
        r += __shfl_xor(r, 1, 16);
        r += __shfl_xor(r, 2, 16);
        r += __shfl_xor(r, 4, 16);
        r += __shfl_xor(r, 8, 16);
        if (l == 0) c2np[code] = r;
    }
    // --- cvt: lane l converts elements l*16 .. l*16+15
    {
        const float* srcv = cb + (size_t)code * DDIM + l * 16;
        _Float16* dstv = cbh + (size_t)code * DDIM + l * 16;
#pragma unroll
        for (int u = 0; u < 2; ++u) {
            float4 v0 = *(const float4*)&srcv[u * 8];
            float4 v1 = *(const float4*)&srcv[u * 8 + 4];
            half8 h;
            h[0] = (_Float16)v0.x; h[1] = (_Float16)v0.y; h[2] = (_Float16)v0.z; h[3] = (_Float16)v0.w;
            h[4] = (_Float16)v1.x; h[5] = (_Float16)v1.y; h[6] = (_Float16)v1.z; h[7] = (_Float16)v1.w;
            *(half8*)&dstv[u * 8] = h;
        }
    }
    if (code == 0 && l == 0) { refCtr[0] = 0; refCtr[1] = 0; refCtr[2] = 0; refCtr[3] = 0; }
}

// ==================== argmin, 128 rows/block: 4 waves x 2 row-tiles, A direct from global ====================
// B tile (64 codes, 32 KB LDS) via global_load_lds with pre-swizzled global source (rule 21).
__global__ __launch_bounds__(256) void argmin128_kernel(const float* __restrict__ E,
                                                        const _Float16* __restrict__ CBH,
                                                        const float* __restrict__ c2,
                                                        int* __restrict__ idxOut,
                                                        float* __restrict__ idxF,
                                                        float* __restrict__ lossPart,
                                                        int* __restrict__ refCtr,
                                                        int4* __restrict__ refQuad,
                                                        int* __restrict__ refFull) {
    __shared__ _Float16 Buf[64 * 256];   // 32 KB B tile
    __shared__ float xsq[128];
    __shared__ float rowd2s[128];
    int tid = threadIdx.x;
    int lane = tid & 63;
    int w = tid >> 6;
    int g = lane >> 4, cl = lane & 15;
    int rowBase = blockIdx.x * 128 + w * 32;

    half8 a[2][8];
#pragma unroll
    for (int rt = 0; rt < 2; ++rt) {
        int row = rowBase + rt * 16 + cl;
        int rg = row < NDIM ? row : NDIM - 1;
        const float* src = E + (size_t)rg * DDIM + g * 8;
        float s = 0.f;
#pragma unroll
        for (int s8 = 0; s8 < 8; ++s8) {
            float4 v0 = *(const float4*)&src[s8 * 32];
            float4 v1 = *(const float4*)&src[s8 * 32 + 4];
            s += v0.x * v0.x + v0.y * v0.y + v0.z * v0.z + v0.w * v0.w;
            s += v1.x * v1.x + v1.y * v1.y + v1.z * v1.z + v1.w * v1.w;
            half8 h;
            h[0] = (_Float16)v0.x; h[1] = (_Float16)v0.y; h[2] = (_Float16)v0.z; h[3] = (_Float16)v0.w;
            h[4] = (_Float16)v1.x; h[5] = (_Float16)v1.y; h[6] = (_Float16)v1.z; h[7] = (_Float16)v1.w;
            a[rt][s8] = h;
        }
        s += __shfl_xor(s, 16, 64);
        s += __shfl_xor(s, 32, 64);
        if (g == 0) xsq[w * 32 + rt * 16 + cl] = s;
    }

    const _Float16* bsrc[8];
    _Float16* bdst[8];
    {
        int rowLoc = lane >> 5;
        int chunk = lane & 31;
#pragma unroll
        for (int i = 0; i < 8; ++i) {
            int row = w * 16 + i * 2 + rowLoc;
            int sc = chunk ^ (row & 7);
            bsrc[i] = CBH + (size_t)row * DDIM + sc * 8;
            bdst[i] = &Buf[(w * 16 + i * 2) * 256];
        }
    }

    float m1[2][4] = {{1e30f, 1e30f, 1e30f, 1e30f}, {1e30f, 1e30f, 1e30f, 1e30f}};
    float m2[2][4] = {{1e30f, 1e30f, 1e30f, 1e30f}, {1e30f, 1e30f, 1e30f, 1e30f}};
    float m3[2][4] = {{1e30f, 1e30f, 1e30f, 1e30f}, {1e30f, 1e30f, 1e30f, 1e30f}};
    int   i1[2][4] = {{0, 0, 0, 0}, {0, 0, 0, 0}};
    int   i2[2][4] = {{0, 0, 0, 0}, {0, 0, 0, 0}};

    for (int kc = 0; kc < 16; ++kc) {
        __syncthreads();
        size_t koff = (size_t)kc * 64 * DDIM;
#pragma unroll
        for (int i = 0; i < 8; ++i) GLD16(bsrc[i] + koff, bdst[i]);
        float cc[4];
#pragma unroll
        for (int t = 0; t < 4; ++t) cc[t] = c2[kc * 64 + t * 16 + cl];
        __syncthreads();

#pragma unroll
        for (int t = 0; t < 4; ++t) {
            int cB = t * 16 + cl;
            int ki = kc * 64 + cB;
#pragma unroll
            for (int rt = 0; rt < 2; ++rt) {
                f32x4 acc = {0.f, 0.f, 0.f, 0.f};
#pragma unroll
                for (int s8 = 0; s8 < 8; ++s8) {
                    int slot = (s8 * 4 + g) ^ (cB & 7);
                    half8 b = *(half8*)&Buf[cB * 256 + slot * 8];
                    acc = __builtin_amdgcn_mfma_f32_16x16x32_f16(a[rt][s8], b, acc, 0, 0, 0);
                }
#pragma unroll
                for (int j = 0; j < 4; ++j) {
                    float v = cc[t] - 2.0f * acc[j];
                    if (v < m1[rt][j])      { m3[rt][j] = m2[rt][j]; m2[rt][j] = m1[rt][j]; i2[rt][j] = i1[rt][j]; m1[rt][j] = v; i1[rt][j] = ki; }
                    else if (v < m2[rt][j]) { m3[rt][j] = m2[rt][j]; m2[rt][j] = v; i2[rt][j] = ki; }
                    else if (v < m3[rt][j]) { m3[rt][j] = v; }
                }
            }
        }
    }
#pragma unroll
    for (int rt = 0; rt < 2; ++rt) {
#pragma unroll
        for (int j = 0; j < 4; ++j) {
            for (int m = 8; m >= 1; m >>= 1) {
                float o1 = __shfl_xor(m1[rt][j], m, 16);
                int   oi1 = __shfl_xor(i1[rt][j], m, 16);
                float o2 = __shfl_xor(m2[rt][j], m, 16);
                int   oi2 = __shfl_xor(i2[rt][j], m, 16);
                float o3 = __shfl_xor(m3[rt][j], m, 16);
                float a1, a2, a3, b1, b2, b3; int ai1, ai2, bi1, bi2;
                if (o1 < m1[rt][j] || (o1 == m1[rt][j] && oi1 < i1[rt][j])) {
                    a1 = o1; ai1 = oi1; a2 = o2; ai2 = oi2; a3 = o3;
                    b1 = m1[rt][j]; bi1 = i1[rt][j]; b2 = m2[rt][j]; bi2 = i2[rt][j]; b3 = m3[rt][j];
                } else {
                    a1 = m1[rt][j]; ai1 = i1[rt][j]; a2 = m2[rt][j]; ai2 = i2[rt][j]; a3 = m3[rt][j];
                    b1 = o1; bi1 = oi1; b2 = o2; bi2 = oi2; b3 = o3;
                }
                (void)bi2; (void)b3;
                m1[rt][j] = a1; i1[rt][j] = ai1;
                if (b1 < a2 || (b1 == a2 && bi1 < ai2)) {
                    m2[rt][j] = b1; i2[rt][j] = bi1; m3[rt][j] = fminf(a2, b2);
                } else {
                    m2[rt][j] = a2; i2[rt][j] = ai2; m3[rt][j] = fminf(a3, b1);
                }
            }
        }
    }
    if (cl == 0) {
#pragma unroll
        for (int rt = 0; rt < 2; ++rt) {
#pragma unroll
            for (int j = 0; j < 4; ++j) {
                int rloc = w * 32 + rt * 16 + g * 4 + j;
                int row = blockIdx.x * 128 + rloc;
                if (row < NDIM) {
                    idxOut[row] = i1[rt][j];
                    idxF[row] = (float)i1[rt][j];
                    rowd2s[rloc] = xsq[rloc] + m1[rt][j];
                    int full = (m3[rt][j] - m1[rt][j] < TAU) ? 1 : 0;
                    if (m2[rt][j] - m1[rt][j] < TAU) {   // ambiguous -> np-exact i1-vs-i2
                        int p = atomicAdd(&refCtr[0], 1);
                        if ((unsigned)p < (unsigned)NDIM) {
                            int4 q; q.x = row; q.y = i1[rt][j]; q.z = i2[rt][j]; q.w = full;
                            refQuad[p] = q;
                        }
                    }
                    if (full) {                          // 3+ close -> full re-scan (w=1 quads skipped by cand path)
                        int p = atomicAdd(&refCtr[1], 1);
                        if ((unsigned)p < (unsigned)NDIM) refFull[p] = row;
                    }
                } else {
                    rowd2s[rloc] = 0.f;
                }
            }
        }
    }
    __syncthreads();
    if (tid == 0) {
        float s = 0.f;
        for (int i = 0; i < 128; ++i) s += rowd2s[i];
        lossPart[blockIdx.x] = s;
    }
}

// ---------------------------------------------------------------- S = query @ codebook^T via fp16 MFMA, K-split grid (64,8)
__global__ __launch_bounds__(256) void sgemm16_kernel(const float* __restrict__ Q,
                                                      const _Float16* __restrict__ CBH,
                                                      float* __restrict__ S) {
    __shared__ _Float16 Buf[64 * 256];
    int tid = threadIdx.x;
    int lane = tid & 63;
    int w = tid >> 6;
    int rowBase = blockIdx.x * 64;
    int kcBase = blockIdx.y * 2;

    {
        int r = tid >> 2, seg = tid & 3;
        const float* src = Q + (size_t)(rowBase + r) * DDIM + seg * 64;
#pragma unroll
        for (int i = 0; i < 8; ++i) {
            float4 v0 = *(const float4*)&src[i * 8];
            float4 v1 = *(const float4*)&src[i * 8 + 4];
            half8 h;
            h[0] = (_Float16)v0.x; h[1] = (_Float16)v0.y; h[2] = (_Float16)v0.z; h[3] = (_Float16)v0.w;
            h[4] = (_Float16)v1.x; h[5] = (_Float16)v1.y; h[6] = (_Float16)v1.z; h[7] = (_Float16)v1.w;
            int slot = (seg * 8 + i) ^ (r & 7);
            *(half8*)&Buf[r * 256 + slot * 8] = h;
        }
    }
    __syncthreads();
    half8 a[8];
    {
        int rA = w * 16 + (lane & 15);
        int g = lane >> 4;
#pragma unroll
        for (int s8 = 0; s8 < 8; ++s8) {
            int slot = (s8 * 4 + g) ^ (rA & 7);
            a[s8] = *(half8*)&Buf[rA * 256 + slot * 8];
        }
    }

    const _Float16* bsrc[8];
    _Float16* bdst[8];
    {
        int rowLoc = lane >> 5;
        int chunk = lane & 31;
#pragma unroll
        for (int i = 0; i < 8; ++i) {
            int row = w * 16 + i * 2 + rowLoc;
            int sc = chunk ^ (row & 7);
            bsrc[i] = CBH + (size_t)row * DDIM + sc * 8;
            bdst[i] = &Buf[(w * 16 + i * 2) * 256];
        }
    }

    for (int kci = 0; kci < 2; ++kci) {
        int kc = kcBase + kci;
        __syncthreads();
        size_t koff = (size_t)kc * 64 * DDIM;
#pragma unroll
        for (int i = 0; i < 8; ++i) GLD16(bsrc[i] + koff, bdst[i]);
        __syncthreads();

        int g = lane >> 4;
#pragma unroll
        for (int t = 0; t < 4; ++t) {
            f32x4 acc = {0.f, 0.f, 0.f, 0.f};
            int cB = t * 16 + (lane & 15);
#pragma unroll
            for (int s8 = 0; s8 < 8; ++s8) {
                int slot = (s8 * 4 + g) ^ (cB & 7);
                half8 b = *(half8*)&Buf[cB * 256 + slot * 8];
                acc = __builtin_amdgcn_mfma_f32_16x16x32_f16(a[s8], b, acc, 0, 0, 0);
            }
#pragma unroll
            for (int j = 0; j < 4; ++j) {
                int row = rowBase + w * 16 + g * 4 + j;
                S[(size_t)row * KDIM + kc * 64 + cB] = acc[j];
            }
        }
    }
}

// ---------------------------------------------------------------- fused tail: refcand (skip w=1) + full re-scan + loss
__global__ __launch_bounds__(256) void reffuse_kernel(const float* __restrict__ E,
                                                      const float* __restrict__ CB,
                                                      const float* __restrict__ c2np,
                                                      const int* __restrict__ refCtr,
                                                      const int4* __restrict__ refQuad,
                                                      const int* __restrict__ refFull,
                                                      int* __restrict__ idxOut,
                                                      float* __restrict__ idxF,
                                                      const float* __restrict__ lossPart,
                                                      float* __restrict__ lossOut) {
    int tid = threadIdx.x;
    // --- part 1: candidate compare, 1 thread per flagged row (rows with w=1 are owned by part 2)
    int c0 = refCtr[0]; if (c0 > NDIM) c0 = NDIM;
    for (int i = blockIdx.x * 256 + tid; i < c0; i += gridDim.x * 256) {
        int4 q = refQuad[i];
        if (q.w) continue;
        int row = q.x, a = q.y, b = q.z;
        const float* xr = E + (size_t)row * DDIM;
        float x2 = np_pairwise_sq(xr);
        float va = np_exact_d2(xr, CB + (size_t)a * DDIM, x2, c2np[a]);
        float vb = np_exact_d2(xr, CB + (size_t)b * DDIM, x2, c2np[b]);
        int win = (vb < va || (vb == va && b < a)) ? b : a;
        idxOut[row] = win;
        idxF[row] = (float)win;
    }
    // --- part 2: full np-exact re-scan, block per row
    __shared__ float xrow[DDIM];
    __shared__ float x2sh;
    __shared__ float wval[4];
    __shared__ int widx[4];
    int c1 = refCtr[1]; if (c1 > NDIM) c1 = NDIM;
    for (int b = blockIdx.x; b < c1; b += gridDim.x) {
        int row = refFull[b];
        xrow[tid] = E[(size_t)row * DDIM + tid];
        __syncthreads();
        if (tid == 0) x2sh = np_pairwise_sq(xrow);
        __syncthreads();
        float best = 1e30f;
        int bidx = 0x7fffffff;
#pragma unroll
        for (int kk = 0; kk < 4; ++kk) {
            int k = tid + kk * 256;
            const float* cp = CB + (size_t)k * DDIM;
            float dot = 0.f;
            for (int d = 0; d < DDIM; ++d) dot = __builtin_fmaf(cp[d], xrow[d], dot);
            float t1 = x2sh + c2np[k];
            float v = t1 - 2.0f * dot;
            if (v < best || (v == best && k < bidx)) { best = v; bidx = k; }
        }
        for (int m = 32; m >= 1; m >>= 1) {
            float ov = __shfl_xor(best, m, 64);
            int   oi = __shfl_xor(bidx, m, 64);
            if (ov < best || (ov == best && oi < bidx)) { best = ov; bidx = oi; }
        }
        if ((tid & 63) == 0) { wval[tid >> 6] = best; widx[tid >> 6] = bidx; }
        __syncthreads();
        if (tid == 0) {
            float bv = wval[0]; int bi = widx[0];
#pragma unroll
            for (int w = 1; w < 4; ++w)
                if (wval[w] < bv || (wval[w] == bv && widx[w] < bi)) { bv = wval[w]; bi = widx[w]; }
            idxOut[row] = bi;
            idxF[row] = (float)bi;
        }
        __syncthreads();
    }
    // --- part 3: loss finalize (block 0, wave 0)
    if (blockIdx.x == 0 && tid < 64) {
        float s = 0.f;
        for (int i = tid; i < ABLK; i += 64) s += lossPart[i];
        for (int m = 32; m >= 1; m >>= 1) s += __shfl_down(s, m, 64);
        if (tid == 0) lossOut[0] = 1.25f * s / (float)(NDIM * DDIM);
    }
}

// ---------------------------------------------------------------- score[q][n] = S[q][idx[n]]  (819 MB streaming NT write)
__global__ __launch_bounds__(256) void gather_kernel(const float* __restrict__ S,
                                                     const int* __restrict__ idx,
                                                     float* __restrict__ score) {
    __shared__ float Srow[4 * 1024];
    int tid = threadIdx.x;
    int qBase = blockIdx.y * 4;
    int nBase = blockIdx.x * 2048;
#pragma unroll
    for (int i = 0; i < 4; ++i) {
        int o = (tid + i * 256) * 4;
        *(float4*)&Srow[o] = *(const float4*)&S[(size_t)qBase * KDIM + o];
    }
    __syncthreads();
#pragma unroll
    for (int s = 0; s < 2; ++s) {
        int n = nBase + s * 1024 + tid * 4;
        if (n < NDIM) {
            int4 id = *(const int4*)&idx[n];
#pragma unroll
            for (int q = 0; q < 4; ++q) {
                const float* sp = &Srow[q * 1024];
                f32x4 v = {sp[id.x], sp[id.y], sp[id.z], sp[id.w]};
                __builtin_nontemporal_store(v, (f32x4*)&score[(size_t)(qBase + q) * NDIM + n]);
            }
        }
    }
}

extern "C" void kernel_launch(void* const* d_in, const int* in_sizes, int n_in,
                              void* d_out, int out_size, void* d_ws, size_t ws_size,
                              hipStream_t stream) {
    const float* query  = (const float*)d_in[0];
    const float* entity = (const float*)d_in[1];
    const float* cb     = (const float*)d_in[2];
    float* out = (float*)d_out;
    char* ws = (char*)d_ws;

    float*     S        = (float*)ws;                   // 16,777,216 B
    float*     c2np     = (float*)(ws + 16777216);      //      4,096 B
    int*       idxW     = (int*)  (ws + 16781312);      //    200,000 B
    int*       refCtr   = (int*)  (ws + 16981312);      //         64 B ([0],[1] real; [2],[3] meter dummies)
    int4*      refQuad  = (int4*) (ws + 16981376);      //    800,000 B
    int*       refFull  = (int*)  (ws + 17781376);      //    200,000 B
    float*     lossPart = (float*)(ws + 17981376);      //      3,128 B
    _Float16*  cbh      = (_Float16*)(ws + 17984512);   //    524,288 B
    // ---- dummy buffers for the argmin128 meter launches
    int*       idx2      = (int*)  (ws + 18508800);     //    200,000 B
    float*     idxF2     = (float*)(ws + 18708800);     //    200,000 B
    int4*      refQuad2  = (int4*) (ws + 18908800);     //    800,000 B
    int*       refFull2  = (int*)  (ws + 19708800);     //    200,000 B
    float*     lossPart2 = (float*)(ws + 19908800);     //      2,048 B

    size_t QN = (size_t)QDIM * NDIM;
    float* score   = out;
    float* lossOut = out + QN;
    float* idxF    = out + QN + 1;

    prepcvt_kernel<<<dim3(KDIM / 16), dim3(256), 0, stream>>>(cb, c2np, cbh, refCtr);
    sgemm16_kernel<<<dim3(QDIM / 64, 8), dim3(256), 0, stream>>>(query, cbh, S);
    argmin128_kernel<<<dim3(ABLK), dim3(256), 0, stream>>>(entity, cbh, c2np, idxW, idxF,
                                                           lossPart, refCtr, refQuad, refFull);
    // ---- meter duplicates (outputs to scratch; dur_us delta = 2 x T_argmin128)
    argmin128_kernel<<<dim3(ABLK), dim3(256), 0, stream>>>(entity, cbh, c2np, idx2, idxF2,
                                                           lossPart2, &refCtr[2], refQuad2, refFull2);
    argmin128_kernel<<<dim3(ABLK), dim3(256), 0, stream>>>(entity, cbh, c2np, idx2, idxF2,
                                                           lossPart2, &refCtr[2], refQuad2, refFull2);
    reffuse_kernel<<<dim3(256), dim3(256), 0, stream>>>(entity, cb, c2np, refCtr, refQuad, refFull,
                                                        idxW, idxF, lossPart, lossOut);
    gather_kernel<<<dim3((NDIM + 2047) / 2048, QDIM / 4), dim3(256), 0, stream>>>(S, idxW, score);
}

// Round 17
// 331.069 us; speedup vs baseline: 1.5034x; 1.5034x over previous
//
#include <hip/hip_runtime.h>

#define QDIM 4096
#define NDIM 50000
#define KDIM 1024
#define DDIM 256
#define ABLK 391          // ceil(NDIM/128) argmin blocks
#define TAU  0.3f         // refine margin: ~10 sigma of the fp16 screen noise

typedef _Float16 half8 __attribute__((ext_vector_type(8)));
typedef float    f32x4 __attribute__((ext_vector_type(4)));

// async global->LDS DMA, 16B per lane, linear LDS dest (base + lane*16)
#define GLD16(srcp, dstp)                                                              \
    __builtin_amdgcn_global_load_lds((const __attribute__((address_space(1))) void*)(srcp), \
                                     (__attribute__((address_space(3))) void*)(dstp), 16, 0, 0)

// ---- emulate numpy pairwise sum of squares for n=256 (two 128-halves, 8 accumulators)
__device__ float np_pairwise_sq(const float* a) {
#pragma clang fp contract(off)
    float res[2];
    for (int h = 0; h < 2; ++h) {
        const float* p = a + h * 128;
        float r0 = p[0] * p[0], r1 = p[1] * p[1], r2 = p[2] * p[2], r3 = p[3] * p[3];
        float r4 = p[4] * p[4], r5 = p[5] * p[5], r6 = p[6] * p[6], r7 = p[7] * p[7];
        for (int i = 8; i < 128; i += 8) {
            r0 += p[i + 0] * p[i + 0];
            r1 += p[i + 1] * p[i + 1];
            r2 += p[i + 2] * p[i + 2];
            r3 += p[i + 3] * p[i + 3];
            r4 += p[i + 4] * p[i + 4];
            r5 += p[i + 5] * p[i + 5];
            r6 += p[i + 6] * p[i + 6];
            r7 += p[i + 7] * p[i + 7];
        }
        res[h] = ((r0 + r1) + (r2 + r3)) + ((r4 + r5) + (r6 + r7));
    }
    return res[0] + res[1];
}

// ---- np-f32-exact d2 for one (row, code) pair
__device__ float np_exact_d2(const float* __restrict__ xr, const float* __restrict__ cp,
                             float x2, float c2v) {
    float dot = 0.f;                         // BLAS-style sequential FMA in d-order
    for (int d = 0; d < DDIM; ++d) dot = __builtin_fmaf(cp[d], xr[d], dot);
    return (x2 + c2v) - 2.0f * dot;
}

// ---------------------------------------------------------------- prep+cvt fused: c2np (bit-exact np tree) + fp16 codebook
__global__ __launch_bounds__(256) void prepcvt_kernel(const float* __restrict__ cb,
                                                      float* __restrict__ c2np,
                                                      _Float16* __restrict__ cbh,
                                                      int* __restrict__ refCtr) {
#pragma clang fp contract(off)
    int tid = threadIdx.x;
    int code = blockIdx.x * 16 + (tid >> 4);
    int l = tid & 15;
    {
        int h = l >> 3, j = l & 7;
        const float* p = cb + (size_t)code * DDIM + h * 128;
        float v0 = p[j];
        float r = v0 * v0;
        for (int i = 8; i < 128; i += 8) { float v = p[i + j]; r = r + v * v; }
        r += __shfl_xor(r, 1, 16);
        r += __shfl_xor(r, 2, 16);
        r += __shfl_xor(r, 4, 16);
        r += __shfl_xor(r, 8, 16);
        if (l == 0) c2np[code] = r;
    }
    {
        const float* srcv = cb + (size_t)code * DDIM + l * 16;
        _Float16* dstv = cbh + (size_t)code * DDIM + l * 16;
#pragma unroll
        for (int u = 0; u < 2; ++u) {
            float4 v0 = *(const float4*)&srcv[u * 8];
            float4 v1 = *(const float4*)&srcv[u * 8 + 4];
            half8 h;
            h[0] = (_Float16)v0.x; h[1] = (_Float16)v0.y; h[2] = (_Float16)v0.z; h[3] = (_Float16)v0.w;
            h[4] = (_Float16)v1.x; h[5] = (_Float16)v1.y; h[6] = (_Float16)v1.z; h[7] = (_Float16)v1.w;
            *(half8*)&dstv[u * 8] = h;
        }
    }
    if (code == 0 && l == 0) { refCtr[0] = 0; refCtr[1] = 0; }
}

// ==================== argmin, 128 rows/block, T3-minimum 2-phase pipeline ====================
// Double-buffered 32 KB B tiles; per chunk: issue next-chunk global_load_lds -> compute current
// -> ONE __syncthreads (drains a mostly-complete vmcnt). c2 staged in LDS to avoid in-order
// vmcnt entanglement with the GLD16 queue. Swizzle as before (rule 21 pre-swizzled source).
__global__ __launch_bounds__(256) void argmin128_kernel(const float* __restrict__ E,
                                                        const _Float16* __restrict__ CBH,
                                                        const float* __restrict__ c2,
                                                        int* __restrict__ idxOut,
                                                        float* __restrict__ idxF,
                                                        float* __restrict__ lossPart,
                                                        int* __restrict__ refCtr,
                                                        int4* __restrict__ refQuad,
                                                        int* __restrict__ refFull) {
    __shared__ _Float16 Buf[2][64 * 256];   // 64 KB double-buffered B tiles
    __shared__ float c2s[KDIM];             // 4 KB c2 copy (lgkm reads, decoupled from vmcnt)
    __shared__ float xsq[128];
    __shared__ float rowd2s[128];
    int tid = threadIdx.x;
    int lane = tid & 63;
    int w = tid >> 6;
    int g = lane >> 4, cl = lane & 15;
    int rowBase = blockIdx.x * 128 + w * 32;

    // ---- A: 2 row-tiles direct global f32 -> fp16 frags in registers; x2 along the way
    half8 a[2][8];
#pragma unroll
    for (int rt = 0; rt < 2; ++rt) {
        int row = rowBase + rt * 16 + cl;
        int rg = row < NDIM ? row : NDIM - 1;
        const float* src = E + (size_t)rg * DDIM + g * 8;
        float s = 0.f;
#pragma unroll
        for (int s8 = 0; s8 < 8; ++s8) {
            float4 v0 = *(const float4*)&src[s8 * 32];
            float4 v1 = *(const float4*)&src[s8 * 32 + 4];
            s += v0.x * v0.x + v0.y * v0.y + v0.z * v0.z + v0.w * v0.w;
            s += v1.x * v1.x + v1.y * v1.y + v1.z * v1.z + v1.w * v1.w;
            half8 h;
            h[0] = (_Float16)v0.x; h[1] = (_Float16)v0.y; h[2] = (_Float16)v0.z; h[3] = (_Float16)v0.w;
            h[4] = (_Float16)v1.x; h[5] = (_Float16)v1.y; h[6] = (_Float16)v1.z; h[7] = (_Float16)v1.w;
            a[rt][s8] = h;
        }
        s += __shfl_xor(s, 16, 64);
        s += __shfl_xor(s, 32, 64);
        if (g == 0) xsq[w * 32 + rt * 16 + cl] = s;
    }

    // ---- per-lane pre-swizzled B sources + LDS dest offsets
    const _Float16* bsrc[8];
    int bdstOff[8];
    {
        int rowLoc = lane >> 5;
        int chunk = lane & 31;
#pragma unroll
        for (int i = 0; i < 8; ++i) {
            int row = w * 16 + i * 2 + rowLoc;
            int sc = chunk ^ (row & 7);
            bsrc[i] = CBH + (size_t)row * DDIM + sc * 8;
            bdstOff[i] = (w * 16 + i * 2) * 256;
        }
    }

    // ---- stage c2 -> LDS (1 float4/thread) and chunk 0 -> Buf[0]
    *(float4*)&c2s[tid * 4] = *(const float4*)&c2[tid * 4];
#pragma unroll
    for (int i = 0; i < 8; ++i) GLD16(bsrc[i], &Buf[0][bdstOff[i]]);
    __syncthreads();                       // Buf[0] + c2s resident

    float m1[2][4] = {{1e30f, 1e30f, 1e30f, 1e30f}, {1e30f, 1e30f, 1e30f, 1e30f}};
    float m2[2][4] = {{1e30f, 1e30f, 1e30f, 1e30f}, {1e30f, 1e30f, 1e30f, 1e30f}};
    float m3[2][4] = {{1e30f, 1e30f, 1e30f, 1e30f}, {1e30f, 1e30f, 1e30f, 1e30f}};
    int   i1[2][4] = {{0, 0, 0, 0}, {0, 0, 0, 0}};
    int   i2[2][4] = {{0, 0, 0, 0}, {0, 0, 0, 0}};

    int cur = 0;
    for (int kc = 0; kc < 16; ++kc) {
        if (kc + 1 < 16) {                 // issue next-chunk loads; they fly under the compute
            size_t koff = (size_t)(kc + 1) * 64 * DDIM;
#pragma unroll
            for (int i = 0; i < 8; ++i) GLD16(bsrc[i] + koff, &Buf[cur ^ 1][bdstOff[i]]);
        }
        float cc[4];
#pragma unroll
        for (int t = 0; t < 4; ++t) cc[t] = c2s[kc * 64 + t * 16 + cl];

#pragma unroll
        for (int t = 0; t < 4; ++t) {
            int cB = t * 16 + cl;
            int ki = kc * 64 + cB;
            half8 bfr[8];
#pragma unroll
            for (int s8 = 0; s8 < 8; ++s8) {
                int slot = (s8 * 4 + g) ^ (cB & 7);
                bfr[s8] = *(half8*)&Buf[cur][cB * 256 + slot * 8];
            }
#pragma unroll
            for (int rt = 0; rt < 2; ++rt) {
                f32x4 acc = {0.f, 0.f, 0.f, 0.f};
#pragma unroll
                for (int s8 = 0; s8 < 8; ++s8)
                    acc = __builtin_amdgcn_mfma_f32_16x16x32_f16(a[rt][s8], bfr[s8], acc, 0, 0, 0);
#pragma unroll
                for (int j = 0; j < 4; ++j) {
                    float v = cc[t] - 2.0f * acc[j];
                    if (v < m1[rt][j])      { m3[rt][j] = m2[rt][j]; m2[rt][j] = m1[rt][j]; i2[rt][j] = i1[rt][j]; m1[rt][j] = v; i1[rt][j] = ki; }
                    else if (v < m2[rt][j]) { m3[rt][j] = m2[rt][j]; m2[rt][j] = v; i2[rt][j] = ki; }
                    else if (v < m3[rt][j]) { m3[rt][j] = v; }
                }
            }
        }
        __syncthreads();                   // next tile resident; all readers of Buf[cur] done
        cur ^= 1;
    }
#pragma unroll
    for (int rt = 0; rt < 2; ++rt) {
#pragma unroll
        for (int j = 0; j < 4; ++j) {
            for (int m = 8; m >= 1; m >>= 1) {
                float o1 = __shfl_xor(m1[rt][j], m, 16);
                int   oi1 = __shfl_xor(i1[rt][j], m, 16);
                float o2 = __shfl_xor(m2[rt][j], m, 16);
                int   oi2 = __shfl_xor(i2[rt][j], m, 16);
                float o3 = __shfl_xor(m3[rt][j], m, 16);
                float a1, a2, a3, b1, b2, b3; int ai1, ai2, bi1, bi2;
                if (o1 < m1[rt][j] || (o1 == m1[rt][j] && oi1 < i1[rt][j])) {
                    a1 = o1; ai1 = oi1; a2 = o2; ai2 = oi2; a3 = o3;
                    b1 = m1[rt][j]; bi1 = i1[rt][j]; b2 = m2[rt][j]; bi2 = i2[rt][j]; b3 = m3[rt][j];
                } else {
                    a1 = m1[rt][j]; ai1 = i1[rt][j]; a2 = m2[rt][j]; ai2 = i2[rt][j]; a3 = m3[rt][j];
                    b1 = o1; bi1 = oi1; b2 = o2; bi2 = oi2; b3 = o3;
                }
                (void)bi2; (void)b3;
                m1[rt][j] = a1; i1[rt][j] = ai1;
                if (b1 < a2 || (b1 == a2 && bi1 < ai2)) {
                    m2[rt][j] = b1; i2[rt][j] = bi1; m3[rt][j] = fminf(a2, b2);
                } else {
                    m2[rt][j] = a2; i2[rt][j] = ai2; m3[rt][j] = fminf(a3, b1);
                }
            }
        }
    }
    if (cl == 0) {
#pragma unroll
        for (int rt = 0; rt < 2; ++rt) {
#pragma unroll
            for (int j = 0; j < 4; ++j) {
                int rloc = w * 32 + rt * 16 + g * 4 + j;
                int row = blockIdx.x * 128 + rloc;
                if (row < NDIM) {
                    idxOut[row] = i1[rt][j];
                    idxF[row] = (float)i1[rt][j];
                    rowd2s[rloc] = xsq[rloc] + m1[rt][j];
                    int full = (m3[rt][j] - m1[rt][j] < TAU) ? 1 : 0;
                    if (m2[rt][j] - m1[rt][j] < TAU) {
                        int p = atomicAdd(&refCtr[0], 1);
                        if ((unsigned)p < (unsigned)NDIM) {
                            int4 q; q.x = row; q.y = i1[rt][j]; q.z = i2[rt][j]; q.w = full;
                            refQuad[p] = q;
                        }
                    }
                    if (full) {
                        int p = atomicAdd(&refCtr[1], 1);
                        if ((unsigned)p < (unsigned)NDIM) refFull[p] = row;
                    }
                } else {
                    rowd2s[rloc] = 0.f;
                }
            }
        }
    }
    __syncthreads();
    if (tid == 0) {
        float s = 0.f;
        for (int i = 0; i < 128; ++i) s += rowd2s[i];
        lossPart[blockIdx.x] = s;
    }
}

// ---------------------------------------------------------------- S = query @ codebook^T via fp16 MFMA, K-split grid (64,8)
__global__ __launch_bounds__(256) void sgemm16_kernel(const float* __restrict__ Q,
                                                      const _Float16* __restrict__ CBH,
                                                      float* __restrict__ S) {
    __shared__ _Float16 Buf[64 * 256];
    int tid = threadIdx.x;
    int lane = tid & 63;
    int w = tid >> 6;
    int rowBase = blockIdx.x * 64;
    int kcBase = blockIdx.y * 2;

    {
        int r = tid >> 2, seg = tid & 3;
        const float* src = Q + (size_t)(rowBase + r) * DDIM + seg * 64;
#pragma unroll
        for (int i = 0; i < 8; ++i) {
            float4 v0 = *(const float4*)&src[i * 8];
            float4 v1 = *(const float4*)&src[i * 8 + 4];
            half8 h;
            h[0] = (_Float16)v0.x; h[1] = (_Float16)v0.y; h[2] = (_Float16)v0.z; h[3] = (_Float16)v0.w;
            h[4] = (_Float16)v1.x; h[5] = (_Float16)v1.y; h[6] = (_Float16)v1.z; h[7] = (_Float16)v1.w;
            int slot = (seg * 8 + i) ^ (r & 7);
            *(half8*)&Buf[r * 256 + slot * 8] = h;
        }
    }
    __syncthreads();
    half8 a[8];
    {
        int rA = w * 16 + (lane & 15);
        int g = lane >> 4;
#pragma unroll
        for (int s8 = 0; s8 < 8; ++s8) {
            int slot = (s8 * 4 + g) ^ (rA & 7);
            a[s8] = *(half8*)&Buf[rA * 256 + slot * 8];
        }
    }

    const _Float16* bsrc[8];
    _Float16* bdst[8];
    {
        int rowLoc = lane >> 5;
        int chunk = lane & 31;
#pragma unroll
        for (int i = 0; i < 8; ++i) {
            int row = w * 16 + i * 2 + rowLoc;
            int sc = chunk ^ (row & 7);
            bsrc[i] = CBH + (size_t)row * DDIM + sc * 8;
            bdst[i] = &Buf[(w * 16 + i * 2) * 256];
        }
    }

    for (int kci = 0; kci < 2; ++kci) {
        int kc = kcBase + kci;
        __syncthreads();
        size_t koff = (size_t)kc * 64 * DDIM;
#pragma unroll
        for (int i = 0; i < 8; ++i) GLD16(bsrc[i] + koff, bdst[i]);
        __syncthreads();

        int g = lane >> 4;
#pragma unroll
        for (int t = 0; t < 4; ++t) {
            f32x4 acc = {0.f, 0.f, 0.f, 0.f};
            int cB = t * 16 + (lane & 15);
#pragma unroll
            for (int s8 = 0; s8 < 8; ++s8) {
                int slot = (s8 * 4 + g) ^ (cB & 7);
                half8 b = *(half8*)&Buf[cB * 256 + slot * 8];
                acc = __builtin_amdgcn_mfma_f32_16x16x32_f16(a[s8], b, acc, 0, 0, 0);
            }
#pragma unroll
            for (int j = 0; j < 4; ++j) {
                int row = rowBase + w * 16 + g * 4 + j;
                S[(size_t)row * KDIM + kc * 64 + cB] = acc[j];
            }
        }
    }
}

// ---------------------------------------------------------------- fused tail: refcand (skip w=1) + full re-scan + loss
__global__ __launch_bounds__(256) void reffuse_kernel(const float* __restrict__ E,
                                                      const float* __restrict__ CB,
                                                      const float* __restrict__ c2np,
                                                      const int* __restrict__ refCtr,
                                                      const int4* __restrict__ refQuad,
                                                      const int* __restrict__ refFull,
                                                      int* __restrict__ idxOut,
                                                      float* __restrict__ idxF,
                                                      const float* __restrict__ lossPart,
                                                      float* __restrict__ lossOut) {
    int tid = threadIdx.x;
    int c0 = refCtr[0]; if (c0 > NDIM) c0 = NDIM;
    for (int i = blockIdx.x * 256 + tid; i < c0; i += gridDim.x * 256) {
        int4 q = refQuad[i];
        if (q.w) continue;
        int row = q.x, a = q.y, b = q.z;
        const float* xr = E + (size_t)row * DDIM;
        float x2 = np_pairwise_sq(xr);
        float va = np_exact_d2(xr, CB + (size_t)a * DDIM, x2, c2np[a]);
        float vb = np_exact_d2(xr, CB + (size_t)b * DDIM, x2, c2np[b]);
        int win = (vb < va || (vb == va && b < a)) ? b : a;
        idxOut[row] = win;
        idxF[row] = (float)win;
    }
    __shared__ float xrow[DDIM];
    __shared__ float x2sh;
    __shared__ float wval[4];
    __shared__ int widx[4];
    int c1 = refCtr[1]; if (c1 > NDIM) c1 = NDIM;
    for (int b = blockIdx.x; b < c1; b += gridDim.x) {
        int row = refFull[b];
        xrow[tid] = E[(size_t)row * DDIM + tid];
        __syncthreads();
        if (tid == 0) x2sh = np_pairwise_sq(xrow);
        __syncthreads();
        float best = 1e30f;
        int bidx = 0x7fffffff;
#pragma unroll
        for (int kk = 0; kk < 4; ++kk) {
            int k = tid + kk * 256;
            const float* cp = CB + (size_t)k * DDIM;
            float dot = 0.f;
            for (int d = 0; d < DDIM; ++d) dot = __builtin_fmaf(cp[d], xrow[d], dot);
            float t1 = x2sh + c2np[k];
            float v = t1 - 2.0f * dot;
            if (v < best || (v == best && k < bidx)) { best = v; bidx = k; }
        }
        for (int m = 32; m >= 1; m >>= 1) {
            float ov = __shfl_xor(best, m, 64);
            int   oi = __shfl_xor(bidx, m, 64);
            if (ov < best || (ov == best && oi < bidx)) { best = ov; bidx = oi; }
        }
        if ((tid & 63) == 0) { wval[tid >> 6] = best; widx[tid >> 6] = bidx; }
        __syncthreads();
        if (tid == 0) {
            float bv = wval[0]; int bi = widx[0];
#pragma unroll
            for (int w = 1; w < 4; ++w)
                if (wval[w] < bv || (wval[w] == bv && widx[w] < bi)) { bv = wval[w]; bi = widx[w]; }
            idxOut[row] = bi;
            idxF[row] = (float)bi;
        }
        __syncthreads();
    }
    if (blockIdx.x == 0 && tid < 64) {
        float s = 0.f;
        for (int i = tid; i < ABLK; i += 64) s += lossPart[i];
        for (int m = 32; m >= 1; m >>= 1) s += __shfl_down(s, m, 64);
        if (tid == 0) lossOut[0] = 1.25f * s / (float)(NDIM * DDIM);
    }
}

// ---------------------------------------------------------------- score[q][n] = S[q][idx[n]]  (819 MB streaming NT write)
__global__ __launch_bounds__(256) void gather_kernel(const float* __restrict__ S,
                                                     const int* __restrict__ idx,
                                                     float* __restrict__ score) {
    __shared__ float Srow[4 * 1024];
    int tid = threadIdx.x;
    int qBase = blockIdx.y * 4;
    int nBase = blockIdx.x * 2048;
#pragma unroll
    for (int i = 0; i < 4; ++i) {
        int o = (tid + i * 256) * 4;
        *(float4*)&Srow[o] = *(const float4*)&S[(size_t)qBase * KDIM + o];
    }
    __syncthreads();
#pragma unroll
    for (int s = 0; s < 2; ++s) {
        int n = nBase + s * 1024 + tid * 4;
        if (n < NDIM) {
            int4 id = *(const int4*)&idx[n];
#pragma unroll
            for (int q = 0; q < 4; ++q) {
                const float* sp = &Srow[q * 1024];
                f32x4 v = {sp[id.x], sp[id.y], sp[id.z], sp[id.w]};
                __builtin_nontemporal_store(v, (f32x4*)&score[(size_t)(qBase + q) * NDIM + n]);
            }
        }
    }
}

extern "C" void kernel_launch(void* const* d_in, const int* in_sizes, int n_in,
                              void* d_out, int out_size, void* d_ws, size_t ws_size,
                              hipStream_t stream) {
    const float* query  = (const float*)d_in[0];
    const float* entity = (const float*)d_in[1];
    const float* cb     = (const float*)d_in[2];
    float* out = (float*)d_out;
    char* ws = (char*)d_ws;

    float*     S        = (float*)ws;                   // 16,777,216 B
    float*     c2np     = (float*)(ws + 16777216);      //      4,096 B
    int*       idxW     = (int*)  (ws + 16781312);      //    200,000 B
    int*       refCtr   = (int*)  (ws + 16981312);      //         64 B
    int4*      refQuad  = (int4*) (ws + 16981376);      //    800,000 B
    int*       refFull  = (int*)  (ws + 17781376);      //    200,000 B
    float*     lossPart = (float*)(ws + 17981376);      //      3,128 B
    _Float16*  cbh      = (_Float16*)(ws + 17984512);   //    524,288 B

    size_t QN = (size_t)QDIM * NDIM;
    float* score   = out;
    float* lossOut = out + QN;
    float* idxF    = out + QN + 1;

    prepcvt_kernel<<<dim3(KDIM / 16), dim3(256), 0, stream>>>(cb, c2np, cbh, refCtr);
    sgemm16_kernel<<<dim3(QDIM / 64, 8), dim3(256), 0, stream>>>(query, cbh, S);
    argmin128_kernel<<<dim3(ABLK), dim3(256), 0, stream>>>(entity, cbh, c2np, idxW, idxF,
                                                           lossPart, refCtr, refQuad, refFull);
    reffuse_kernel<<<dim3(256), dim3(256), 0, stream>>>(entity, cb, c2np, refCtr, refQuad, refFull,
                                                        idxW, idxF, lossPart, lossOut);
    gather_kernel<<<dim3((NDIM + 2047) / 2048, QDIM / 4), dim3(256), 0, stream>>>(S, idxW, score);
}

// Round 18
// 320.712 us; speedup vs baseline: 1.5519x; 1.0323x over previous
//
#include <hip/hip_runtime.h>

#define QDIM 4096
#define NDIM 50000
#define KDIM 1024
#define DDIM 256
#define ABLK 391          // ceil(NDIM/128) argmin blocks
#define SBLK 512          // sgemm blocks: 64 row-tiles x 8 kc-pairs
#define TAU  0.3f         // refine margin: ~10 sigma of the fp16 screen noise

typedef _Float16 half8 __attribute__((ext_vector_type(8)));
typedef float    f32x4 __attribute__((ext_vector_type(4)));

// async global->LDS DMA, 16B per lane, linear LDS dest (base + lane*16)
#define GLD16(srcp, dstp)                                                              \
    __builtin_amdgcn_global_load_lds((const __attribute__((address_space(1))) void*)(srcp), \
                                     (__attribute__((address_space(3))) void*)(dstp), 16, 0, 0)

// ---- emulate numpy pairwise sum of squares for n=256 (two 128-halves, 8 accumulators)
__device__ float np_pairwise_sq(const float* a) {
#pragma clang fp contract(off)
    float res[2];
    for (int h = 0; h < 2; ++h) {
        const float* p = a + h * 128;
        float r0 = p[0] * p[0], r1 = p[1] * p[1], r2 = p[2] * p[2], r3 = p[3] * p[3];
        float r4 = p[4] * p[4], r5 = p[5] * p[5], r6 = p[6] * p[6], r7 = p[7] * p[7];
        for (int i = 8; i < 128; i += 8) {
            r0 += p[i + 0] * p[i + 0];
            r1 += p[i + 1] * p[i + 1];
            r2 += p[i + 2] * p[i + 2];
            r3 += p[i + 3] * p[i + 3];
            r4 += p[i + 4] * p[i + 4];
            r5 += p[i + 5] * p[i + 5];
            r6 += p[i + 6] * p[i + 6];
            r7 += p[i + 7] * p[i + 7];
        }
        res[h] = ((r0 + r1) + (r2 + r3)) + ((r4 + r5) + (r6 + r7));
    }
    return res[0] + res[1];
}

// ---- np-f32-exact d2 for one (row, code) pair
__device__ float np_exact_d2(const float* __restrict__ xr, const float* __restrict__ cp,
                             float x2, float c2v) {
    float dot = 0.f;                         // BLAS-style sequential FMA in d-order
    for (int d = 0; d < DDIM; ++d) dot = __builtin_fmaf(cp[d], xr[d], dot);
    return (x2 + c2v) - 2.0f * dot;
}

// ---------------------------------------------------------------- prep+cvt fused: c2np (bit-exact np tree) + fp16 codebook
__global__ __launch_bounds__(256) void prepcvt_kernel(const float* __restrict__ cb,
                                                      float* __restrict__ c2np,
                                                      _Float16* __restrict__ cbh,
                                                      int* __restrict__ refCtr) {
#pragma clang fp contract(off)
    int tid = threadIdx.x;
    int code = blockIdx.x * 16 + (tid >> 4);
    int l = tid & 15;
    {
        int h = l >> 3, j = l & 7;
        const float* p = cb + (size_t)code * DDIM + h * 128;
        float v0 = p[j];
        float r = v0 * v0;
        for (int i = 8; i < 128; i += 8) { float v = p[i + j]; r = r + v * v; }
        r += __shfl_xor(r, 1, 16);
        r += __shfl_xor(r, 2, 16);
        r += __shfl_xor(r, 4, 16);
        r += __shfl_xor(r, 8, 16);
        if (l == 0) c2np[code] = r;
    }
    {
        const float* srcv = cb + (size_t)code * DDIM + l * 16;
        _Float16* dstv = cbh + (size_t)code * DDIM + l * 16;
#pragma unroll
        for (int u = 0; u < 2; ++u) {
            float4 v0 = *(const float4*)&srcv[u * 8];
            float4 v1 = *(const float4*)&srcv[u * 8 + 4];
            half8 h;
            h[0] = (_Float16)v0.x; h[1] = (_Float16)v0.y; h[2] = (_Float16)v0.z; h[3] = (_Float16)v0.w;
            h[4] = (_Float16)v1.x; h[5] = (_Float16)v1.y; h[6] = (_Float16)v1.z; h[7] = (_Float16)v1.w;
            *(half8*)&dstv[u * 8] = h;
        }
    }
    if (code == 0 && l == 0) { refCtr[0] = 0; refCtr[1] = 0; }
}

// ==================== fused main: blocks [0,ABLK) = argmin128 (r17-verbatim), [ABLK,ABLK+SBLK) = sgemm16 ====================
// argmin blocks first: longest work dispatches first; sgemm blocks fill CU slots behind them.
__global__ __launch_bounds__(256) void main_kernel(const float* __restrict__ E,
                                                   const float* __restrict__ Q,
                                                   const _Float16* __restrict__ CBH,
                                                   const float* __restrict__ c2,
                                                   float* __restrict__ S,
                                                   int* __restrict__ idxOut,
                                                   float* __restrict__ idxF,
                                                   float* __restrict__ lossPart,
                                                   int* __restrict__ refCtr,
                                                   int4* __restrict__ refQuad,
                                                   int* __restrict__ refFull) {
    __shared__ _Float16 Buf[2][64 * 256];   // argmin: dbuf; sgemm: Buf[0] only
    __shared__ float c2s[KDIM];
    __shared__ float xsq[128];
    __shared__ float rowd2s[128];
    int tid = threadIdx.x;
    int lane = tid & 63;
    int w = tid >> 6;
    int g = lane >> 4, cl = lane & 15;

    if (blockIdx.x < ABLK) {
        // ================= argmin path (r17 byte-identical) =================
        int rowBase = blockIdx.x * 128 + w * 32;

        half8 a[2][8];
#pragma unroll
        for (int rt = 0; rt < 2; ++rt) {
            int row = rowBase + rt * 16 + cl;
            int rg = row < NDIM ? row : NDIM - 1;
            const float* src = E + (size_t)rg * DDIM + g * 8;
            float s = 0.f;
#pragma unroll
            for (int s8 = 0; s8 < 8; ++s8) {
                float4 v0 = *(const float4*)&src[s8 * 32];
                float4 v1 = *(const float4*)&src[s8 * 32 + 4];
                s += v0.x * v0.x + v0.y * v0.y + v0.z * v0.z + v0.w * v0.w;
                s += v1.x * v1.x + v1.y * v1.y + v1.z * v1.z + v1.w * v1.w;
                half8 h;
                h[0] = (_Float16)v0.x; h[1] = (_Float16)v0.y; h[2] = (_Float16)v0.z; h[3] = (_Float16)v0.w;
                h[4] = (_Float16)v1.x; h[5] = (_Float16)v1.y; h[6] = (_Float16)v1.z; h[7] = (_Float16)v1.w;
                a[rt][s8] = h;
            }
            s += __shfl_xor(s, 16, 64);
            s += __shfl_xor(s, 32, 64);
            if (g == 0) xsq[w * 32 + rt * 16 + cl] = s;
        }

        const _Float16* bsrc[8];
        int bdstOff[8];
        {
            int rowLoc = lane >> 5;
            int chunk = lane & 31;
#pragma unroll
            for (int i = 0; i < 8; ++i) {
                int row = w * 16 + i * 2 + rowLoc;
                int sc = chunk ^ (row & 7);
                bsrc[i] = CBH + (size_t)row * DDIM + sc * 8;
                bdstOff[i] = (w * 16 + i * 2) * 256;
            }
        }

        *(float4*)&c2s[tid * 4] = *(const float4*)&c2[tid * 4];
#pragma unroll
        for (int i = 0; i < 8; ++i) GLD16(bsrc[i], &Buf[0][bdstOff[i]]);
        __syncthreads();

        float m1[2][4] = {{1e30f, 1e30f, 1e30f, 1e30f}, {1e30f, 1e30f, 1e30f, 1e30f}};
        float m2[2][4] = {{1e30f, 1e30f, 1e30f, 1e30f}, {1e30f, 1e30f, 1e30f, 1e30f}};
        float m3[2][4] = {{1e30f, 1e30f, 1e30f, 1e30f}, {1e30f, 1e30f, 1e30f, 1e30f}};
        int   i1[2][4] = {{0, 0, 0, 0}, {0, 0, 0, 0}};
        int   i2[2][4] = {{0, 0, 0, 0}, {0, 0, 0, 0}};

        int cur = 0;
        for (int kc = 0; kc < 16; ++kc) {
            if (kc + 1 < 16) {
                size_t koff = (size_t)(kc + 1) * 64 * DDIM;
#pragma unroll
                for (int i = 0; i < 8; ++i) GLD16(bsrc[i] + koff, &Buf[cur ^ 1][bdstOff[i]]);
            }
            float cc[4];
#pragma unroll
            for (int t = 0; t < 4; ++t) cc[t] = c2s[kc * 64 + t * 16 + cl];

#pragma unroll
            for (int t = 0; t < 4; ++t) {
                int cB = t * 16 + cl;
                int ki = kc * 64 + cB;
                half8 bfr[8];
#pragma unroll
                for (int s8 = 0; s8 < 8; ++s8) {
                    int slot = (s8 * 4 + g) ^ (cB & 7);
                    bfr[s8] = *(half8*)&Buf[cur][cB * 256 + slot * 8];
                }
#pragma unroll
                for (int rt = 0; rt < 2; ++rt) {
                    f32x4 acc = {0.f, 0.f, 0.f, 0.f};
#pragma unroll
                    for (int s8 = 0; s8 < 8; ++s8)
                        acc = __builtin_amdgcn_mfma_f32_16x16x32_f16(a[rt][s8], bfr[s8], acc, 0, 0, 0);
#pragma unroll
                    for (int j = 0; j < 4; ++j) {
                        float v = cc[t] - 2.0f * acc[j];
                        if (v < m1[rt][j])      { m3[rt][j] = m2[rt][j]; m2[rt][j] = m1[rt][j]; i2[rt][j] = i1[rt][j]; m1[rt][j] = v; i1[rt][j] = ki; }
                        else if (v < m2[rt][j]) { m3[rt][j] = m2[rt][j]; m2[rt][j] = v; i2[rt][j] = ki; }
                        else if (v < m3[rt][j]) { m3[rt][j] = v; }
                    }
                }
            }
            __syncthreads();
            cur ^= 1;
        }
#pragma unroll
        for (int rt = 0; rt < 2; ++rt) {
#pragma unroll
            for (int j = 0; j < 4; ++j) {
                for (int m = 8; m >= 1; m >>= 1) {
                    float o1 = __shfl_xor(m1[rt][j], m, 16);
                    int   oi1 = __shfl_xor(i1[rt][j], m, 16);
                    float o2 = __shfl_xor(m2[rt][j], m, 16);
                    int   oi2 = __shfl_xor(i2[rt][j], m, 16);
                    float o3 = __shfl_xor(m3[rt][j], m, 16);
                    float a1, a2, a3, b1, b2, b3; int ai1, ai2, bi1, bi2;
                    if (o1 < m1[rt][j] || (o1 == m1[rt][j] && oi1 < i1[rt][j])) {
                        a1 = o1; ai1 = oi1; a2 = o2; ai2 = oi2; a3 = o3;
                        b1 = m1[rt][j]; bi1 = i1[rt][j]; b2 = m2[rt][j]; bi2 = i2[rt][j]; b3 = m3[rt][j];
                    } else {
                        a1 = m1[rt][j]; ai1 = i1[rt][j]; a2 = m2[rt][j]; ai2 = i2[rt][j]; a3 = m3[rt][j];
                        b1 = o1; bi1 = oi1; b2 = o2; bi2 = oi2; b3 = o3;
                    }
                    (void)bi2; (void)b3;
                    m1[rt][j] = a1; i1[rt][j] = ai1;
                    if (b1 < a2 || (b1 == a2 && bi1 < ai2)) {
                        m2[rt][j] = b1; i2[rt][j] = bi1; m3[rt][j] = fminf(a2, b2);
                    } else {
                        m2[rt][j] = a2; i2[rt][j] = ai2; m3[rt][j] = fminf(a3, b1);
                    }
                }
            }
        }
        if (cl == 0) {
#pragma unroll
            for (int rt = 0; rt < 2; ++rt) {
#pragma unroll
                for (int j = 0; j < 4; ++j) {
                    int rloc = w * 32 + rt * 16 + g * 4 + j;
                    int row = blockIdx.x * 128 + rloc;
                    if (row < NDIM) {
                        idxOut[row] = i1[rt][j];
                        idxF[row] = (float)i1[rt][j];
                        rowd2s[rloc] = xsq[rloc] + m1[rt][j];
                        int full = (m3[rt][j] - m1[rt][j] < TAU) ? 1 : 0;
                        if (m2[rt][j] - m1[rt][j] < TAU) {
                            int p = atomicAdd(&refCtr[0], 1);
                            if ((unsigned)p < (unsigned)NDIM) {
                                int4 q; q.x = row; q.y = i1[rt][j]; q.z = i2[rt][j]; q.w = full;
                                refQuad[p] = q;
                            }
                        }
                        if (full) {
                            int p = atomicAdd(&refCtr[1], 1);
                            if ((unsigned)p < (unsigned)NDIM) refFull[p] = row;
                        }
                    } else {
                        rowd2s[rloc] = 0.f;
                    }
                }
            }
        }
        __syncthreads();
        if (tid == 0) {
            float s = 0.f;
            for (int i = 0; i < 128; ++i) s += rowd2s[i];
            lossPart[blockIdx.x] = s;
        }
    } else {
        // ================= sgemm path (r17 byte-identical on Buf[0]; kc-major bx for L2) =================
        int bx = blockIdx.x - ABLK;
        int rowBase = (bx & 63) * 64;
        int kcBase = (bx >> 6) * 2;

        {
            int r = tid >> 2, seg = tid & 3;
            const float* src = Q + (size_t)(rowBase + r) * DDIM + seg * 64;
#pragma unroll
            for (int i = 0; i < 8; ++i) {
                float4 v0 = *(const float4*)&src[i * 8];
                float4 v1 = *(const float4*)&src[i * 8 + 4];
                half8 h;
                h[0] = (_Float16)v0.x; h[1] = (_Float16)v0.y; h[2] = (_Float16)v0.z; h[3] = (_Float16)v0.w;
                h[4] = (_Float16)v1.x; h[5] = (_Float16)v1.y; h[6] = (_Float16)v1.z; h[7] = (_Float16)v1.w;
                int slot = (seg * 8 + i) ^ (r & 7);
                *(half8*)&Buf[0][r * 256 + slot * 8] = h;
            }
        }
        __syncthreads();
        half8 a[8];
        {
            int rA = w * 16 + cl;
#pragma unroll
            for (int s8 = 0; s8 < 8; ++s8) {
                int slot = (s8 * 4 + g) ^ (rA & 7);
                a[s8] = *(half8*)&Buf[0][rA * 256 + slot * 8];
            }
        }

        const _Float16* bsrc[8];
        _Float16* bdst[8];
        {
            int rowLoc = lane >> 5;
            int chunk = lane & 31;
#pragma unroll
            for (int i = 0; i < 8; ++i) {
                int row = w * 16 + i * 2 + rowLoc;
                int sc = chunk ^ (row & 7);
                bsrc[i] = CBH + (size_t)row * DDIM + sc * 8;
                bdst[i] = &Buf[0][(w * 16 + i * 2) * 256];
            }
        }

        for (int kci = 0; kci < 2; ++kci) {
            int kc = kcBase + kci;
            __syncthreads();
            size_t koff = (size_t)kc * 64 * DDIM;
#pragma unroll
            for (int i = 0; i < 8; ++i) GLD16(bsrc[i] + koff, bdst[i]);
            __syncthreads();

#pragma unroll
            for (int t = 0; t < 4; ++t) {
                f32x4 acc = {0.f, 0.f, 0.f, 0.f};
                int cB = t * 16 + cl;
#pragma unroll
                for (int s8 = 0; s8 < 8; ++s8) {
                    int slot = (s8 * 4 + g) ^ (cB & 7);
                    half8 b = *(half8*)&Buf[0][cB * 256 + slot * 8];
                    acc = __builtin_amdgcn_mfma_f32_16x16x32_f16(a[s8], b, acc, 0, 0, 0);
                }
#pragma unroll
                for (int j = 0; j < 4; ++j) {
                    int row = rowBase + w * 16 + g * 4 + j;
                    S[(size_t)row * KDIM + kc * 64 + cB] = acc[j];
                }
            }
        }
    }
}

// ---------------------------------------------------------------- fused tail: refcand (skip w=1) + full re-scan + loss
__global__ __launch_bounds__(256) void reffuse_kernel(const float* __restrict__ E,
                                                      const float* __restrict__ CB,
                                                      const float* __restrict__ c2np,
                                                      const int* __restrict__ refCtr,
                                                      const int4* __restrict__ refQuad,
                                                      const int* __restrict__ refFull,
                                                      int* __restrict__ idxOut,
                                                      float* __restrict__ idxF,
                                                      const float* __restrict__ lossPart,
                                                      float* __restrict__ lossOut) {
    int tid = threadIdx.x;
    int c0 = refCtr[0]; if (c0 > NDIM) c0 = NDIM;
    for (int i = blockIdx.x * 256 + tid; i < c0; i += gridDim.x * 256) {
        int4 q = refQuad[i];
        if (q.w) continue;
        int row = q.x, a = q.y, b = q.z;
        const float* xr = E + (size_t)row * DDIM;
        float x2 = np_pairwise_sq(xr);
        float va = np_exact_d2(xr, CB + (size_t)a * DDIM, x2, c2np[a]);
        float vb = np_exact_d2(xr, CB + (size_t)b * DDIM, x2, c2np[b]);
        int win = (vb < va || (vb == va && b < a)) ? b : a;
        idxOut[row] = win;
        idxF[row] = (float)win;
    }
    __shared__ float xrow[DDIM];
    __shared__ float x2sh;
    __shared__ float wval[4];
    __shared__ int widx[4];
    int c1 = refCtr[1]; if (c1 > NDIM) c1 = NDIM;
    for (int b = blockIdx.x; b < c1; b += gridDim.x) {
        int row = refFull[b];
        xrow[tid] = E[(size_t)row * DDIM + tid];
        __syncthreads();
        if (tid == 0) x2sh = np_pairwise_sq(xrow);
        __syncthreads();
        float best = 1e30f;
        int bidx = 0x7fffffff;
#pragma unroll
        for (int kk = 0; kk < 4; ++kk) {
            int k = tid + kk * 256;
            const float* cp = CB + (size_t)k * DDIM;
            float dot = 0.f;
            for (int d = 0; d < DDIM; ++d) dot = __builtin_fmaf(cp[d], xrow[d], dot);
            float t1 = x2sh + c2np[k];
            float v = t1 - 2.0f * dot;
            if (v < best || (v == best && k < bidx)) { best = v; bidx = k; }
        }
        for (int m = 32; m >= 1; m >>= 1) {
            float ov = __shfl_xor(best, m, 64);
            int   oi = __shfl_xor(bidx, m, 64);
            if (ov < best || (ov == best && oi < bidx)) { best = ov; bidx = oi; }
        }
        if ((tid & 63) == 0) { wval[tid >> 6] = best; widx[tid >> 6] = bidx; }
        __syncthreads();
        if (tid == 0) {
            float bv = wval[0]; int bi = widx[0];
#pragma unroll
            for (int w = 1; w < 4; ++w)
                if (wval[w] < bv || (wval[w] == bv && widx[w] < bi)) { bv = wval[w]; bi = widx[w]; }
            idxOut[row] = bi;
            idxF[row] = (float)bi;
        }
        __syncthreads();
    }
    if (blockIdx.x == 0 && tid < 64) {
        float s = 0.f;
        for (int i = tid; i < ABLK; i += 64) s += lossPart[i];
        for (int m = 32; m >= 1; m >>= 1) s += __shfl_down(s, m, 64);
        if (tid == 0) lossOut[0] = 1.25f * s / (float)(NDIM * DDIM);
    }
}

// ---------------------------------------------------------------- score[q][n] = S[q][idx[n]]  (819 MB streaming NT write)
__global__ __launch_bounds__(256) void gather_kernel(const float* __restrict__ S,
                                                     const int* __restrict__ idx,
                                                     float* __restrict__ score) {
    __shared__ float Srow[4 * 1024];
    int tid = threadIdx.x;
    int qBase = blockIdx.y * 4;
    int nBase = blockIdx.x * 2048;
#pragma unroll
    for (int i = 0; i < 4; ++i) {
        int o = (tid + i * 256) * 4;
        *(float4*)&Srow[o] = *(const float4*)&S[(size_t)qBase * KDIM + o];
    }
    __syncthreads();
#pragma unroll
    for (int s = 0; s < 2; ++s) {
        int n = nBase + s * 1024 + tid * 4;
        if (n < NDIM) {
            int4 id = *(const int4*)&idx[n];
#pragma unroll
            for (int q = 0; q < 4; ++q) {
                const float* sp = &Srow[q * 1024];
                f32x4 v = {sp[id.x], sp[id.y], sp[id.z], sp[id.w]};
                __builtin_nontemporal_store(v, (f32x4*)&score[(size_t)(qBase + q) * NDIM + n]);
            }
        }
    }
}

extern "C" void kernel_launch(void* const* d_in, const int* in_sizes, int n_in,
                              void* d_out, int out_size, void* d_ws, size_t ws_size,
                              hipStream_t stream) {
    const float* query  = (const float*)d_in[0];
    const float* entity = (const float*)d_in[1];
    const float* cb     = (const float*)d_in[2];
    float* out = (float*)d_out;
    char* ws = (char*)d_ws;

    float*     S        = (float*)ws;                   // 16,777,216 B
    float*     c2np     = (float*)(ws + 16777216);      //      4,096 B
    int*       idxW     = (int*)  (ws + 16781312);      //    200,000 B
    int*       refCtr   = (int*)  (ws + 16981312);      //         64 B
    int4*      refQuad  = (int4*) (ws + 16981376);      //    800,000 B
    int*       refFull  = (int*)  (ws + 17781376);      //    200,000 B
    float*     lossPart = (float*)(ws + 17981376);      //      3,128 B
    _Float16*  cbh      = (_Float16*)(ws + 17984512);   //    524,288 B

    size_t QN = (size_t)QDIM * NDIM;
    float* score   = out;
    float* lossOut = out + QN;
    float* idxF    = out + QN + 1;

    prepcvt_kernel<<<dim3(KDIM / 16), dim3(256), 0, stream>>>(cb, c2np, cbh, refCtr);
    main_kernel<<<dim3(ABLK + SBLK), dim3(256), 0, stream>>>(entity, query, cbh, c2np, S,
                                                             idxW, idxF, lossPart,
                                                             refCtr, refQuad, refFull);
    reffuse_kernel<<<dim3(256), dim3(256), 0, stream>>>(entity, cb, c2np, refCtr, refQuad, refFull,
                                                        idxW, idxF, lossPart, lossOut);
    gather_kernel<<<dim3((NDIM + 2047) / 2048, QDIM / 4), dim3(256), 0, stream>>>(S, idxW, score);
}